// Round 10
// baseline (439.517 us; speedup 1.0000x reference)
//
#include <hip/hip_runtime.h>

// ---------------------------------------------------------------------------
// GCN forward, pull-based + fused. A(HW) = (AH)W:
//   per layer one kernel: gather A·H rows into LDS, then 128x128 matvec with
//   W staged in two 32 KiB halves (48 KiB LDS -> 3 blocks/CU at 512 thr).
//   Gather: CSR rows padded to x8 records; per 32-lane group two rows; ONE
//   coalesced record load (lanes 0-7 row0 chunk, 8-15 row1 chunk) + shfl
//   broadcast -> 16 row-loads per record-load (vmem-issue overhead ~6%).
//   Layer 4's matvec commutes past the mean-pool:
//   out = mean(agg4)·(W4·Wlin) + (b4·Wlin + blin); layer 4 = pure gather,
//   then segmented mean-pool (batch sorted).
// ---------------------------------------------------------------------------

__global__ void k_count(const int* __restrict__ dstv, int E, int* __restrict__ cnt) {
    int e = blockIdx.x * blockDim.x + threadIdx.x;
    if (e < E) atomicAdd(&cnt[dstv[e]], 1);
}

// scan over PADDED counts ((deg+7)&~7); also emits dinv from raw deg
__global__ void k_scan1(const int* __restrict__ cnt, int N,
                        int* __restrict__ rowptr, int* __restrict__ bsums,
                        float* __restrict__ dinv) {
    __shared__ int sh[256];
    const int t = threadIdx.x;
    const int i = blockIdx.x * 256 + t;
    const int v = (i < N) ? cnt[i] : 0;
    const int pv = (v + 7) & ~7;
    if (i < N) dinv[i] = 1.0f / sqrtf((float)(v + 1));  // +1 self loop
    sh[t] = pv;
    __syncthreads();
    for (int off = 1; off < 256; off <<= 1) {
        int add = (t >= off) ? sh[t - off] : 0;
        __syncthreads();
        sh[t] += add;
        __syncthreads();
    }
    if (i < N) rowptr[i] = sh[t] - pv;
    if (t == 255) bsums[blockIdx.x] = sh[255];
}

__global__ void k_scan2(int* __restrict__ bsums, int nb) {
    __shared__ int sh[256];
    const int t = threadIdx.x;
    const int v = (t < nb) ? bsums[t] : 0;
    sh[t] = v;
    __syncthreads();
    for (int off = 1; off < 256; off <<= 1) {
        int add = (t >= off) ? sh[t - off] : 0;
        __syncthreads();
        sh[t] += add;
        __syncthreads();
    }
    if (t < nb) bsums[t] = sh[t] - v;
}

__global__ void k_scan3(int* __restrict__ rowptr, const int* __restrict__ bsums,
                        int* __restrict__ cnt, int N) {
    const int i = blockIdx.x * blockDim.x + threadIdx.x;
    if (i < N) {
        rowptr[i] += bsums[i >> 8];
        if (i == N - 1) rowptr[N] = rowptr[i] + ((cnt[i] + 7) & ~7);
        cnt[i] = 0;                            // becomes fill cursor
    }
}

// packed edge record: .x = src index (bit pattern), .y = dinv[src]*dinv[dst]
// pad slots (memset to 0) = {src 0, weight 0.0}
__global__ void k_fill(const int* __restrict__ srcv, const int* __restrict__ dstv,
                       const int* __restrict__ rowptr, int* __restrict__ cur,
                       const float* __restrict__ dinv,
                       float2* __restrict__ csr_pack, int E) {
    int e = blockIdx.x * blockDim.x + threadIdx.x;
    if (e < E) {
        const int d = dstv[e];
        const int s = srcv[e];
        const int slot = atomicAdd(&cur[d], 1);
        float2 rec;
        rec.x = __int_as_float(s);
        rec.y = dinv[s] * dinv[d];
        csr_pack[rowptr[d] + slot] = rec;
    }
}

__global__ void k_bounds(const int* __restrict__ batch, int N, int G,
                         int* __restrict__ start) {
    const int g = blockIdx.x * blockDim.x + threadIdx.x;
    if (g > G) return;
    int lo = 0, hi = N;
    while (lo < hi) {
        const int mid = (lo + hi) >> 1;
        if (batch[mid] < g) lo = mid + 1; else hi = mid;
    }
    start[g] = lo;
}

// Wc = W4 @ Wlin (128 x T), bc = b4 @ Wlin + blin (T)
__global__ void k_combine(const float* __restrict__ W4, const float* __restrict__ Wlin,
                          const float* __restrict__ b4, const float* __restrict__ blin,
                          float* __restrict__ Wc, float* __restrict__ bc, int T) {
    const int idx = blockIdx.x * blockDim.x + threadIdx.x;
    if (idx < 128 * T) {
        const int k = idx / T, t = idx % T;
        float acc = 0.f;
        #pragma unroll 8
        for (int j = 0; j < 128; ++j)
            acc = fmaf(W4[k * 128 + j], Wlin[j * T + t], acc);
        Wc[idx] = acc;
    }
    if (idx < T) {
        float acc = blin[idx];
        #pragma unroll 8
        for (int j = 0; j < 128; ++j)
            acc = fmaf(b4[j], Wlin[j * T + idx], acc);
        bc[idx] = acc;
    }
}

__device__ __forceinline__ void fma4(float4& acc, float s, const float4& w) {
    acc.x = fmaf(s, w.x, acc.x);
    acc.y = fmaf(s, w.y, acc.y);
    acc.z = fmaf(s, w.z, acc.z);
    acc.w = fmaf(s, w.w, acc.w);
}

// Gather aggregated rows n0 AND n1. Per while-iter: ONE coalesced record
// load (lanes 0-7 = row0's 8-chunk, lanes 8-15 = row1's, lanes 16-31 dummy),
// shfl-broadcast idx+w, then 16 independent row loads. Rows padded to x8;
// exhausted rows redirect their chunk to the dummy zero-chunk.
__device__ __forceinline__ void gather_pair8(
    int n0, int n1, int v0, int v1,
    const float* __restrict__ Hin,
    const int* __restrict__ rowptr, const float2* __restrict__ pk,
    const float* __restrict__ dinv, int lane, int dummy,
    float4& r0, float4& r1)
{
    const int nc0 = v0 ? n0 : 0;
    const int nc1 = v1 ? n1 : 0;
    const float dn0 = v0 ? dinv[nc0] : 0.f;
    const float dn1 = v1 ? dinv[nc1] : 0.f;
    int c0 = rowptr[nc0];
    int c1 = rowptr[nc1];
    const int e0 = v0 ? rowptr[nc0 + 1] : c0;
    const int e1 = v1 ? rowptr[nc1 + 1] : c1;

    const float4 s0v = *(const float4*)(Hin + (size_t)nc0 * 128 + 4 * lane);
    const float4 s1v = *(const float4*)(Hin + (size_t)nc1 * 128 + 4 * lane);
    const float sw0 = dn0 * dn0, sw1 = dn1 * dn1;
    float4 p0 = make_float4(s0v.x * sw0, s0v.y * sw0, s0v.z * sw0, s0v.w * sw0);
    float4 q0 = make_float4(s1v.x * sw1, s1v.y * sw1, s1v.z * sw1, s1v.w * sw1);
    float4 p1 = make_float4(0.f, 0.f, 0.f, 0.f);
    float4 q1 = make_float4(0.f, 0.f, 0.f, 0.f);

    while (c0 < e0 || c1 < e1) {
        const int b0 = (c0 < e0) ? c0 : dummy;   // chunk-level select only
        const int b1 = (c1 < e1) ? c1 : dummy;
        const int jl = (lane < 8) ? (b0 + lane)
                     : ((lane < 16) ? (b1 + lane - 8) : (dummy + (lane & 7)));
        const float2 rec = pk[jl];               // one coalesced 8B/lane load
        const int   si = __float_as_int(rec.x);
        const float wv = rec.y;
        #pragma unroll
        for (int k = 0; k < 8; k += 2) {
            const int   i00 = __shfl(si, k, 32);
            const float w00 = __shfl(wv, k, 32);
            const int   i01 = __shfl(si, k + 1, 32);
            const float w01 = __shfl(wv, k + 1, 32);
            const int   i10 = __shfl(si, k + 8, 32);
            const float w10 = __shfl(wv, k + 8, 32);
            const int   i11 = __shfl(si, k + 9, 32);
            const float w11 = __shfl(wv, k + 9, 32);
            const float4 va0 = *(const float4*)(Hin + (size_t)i00 * 128 + 4 * lane);
            const float4 va1 = *(const float4*)(Hin + (size_t)i01 * 128 + 4 * lane);
            const float4 vb0 = *(const float4*)(Hin + (size_t)i10 * 128 + 4 * lane);
            const float4 vb1 = *(const float4*)(Hin + (size_t)i11 * 128 + 4 * lane);
            fma4(p0, w00, va0); fma4(p1, w01, va1);
            fma4(q0, w10, vb0); fma4(q1, w11, vb1);
        }
        c0 += 8; c1 += 8;
    }
    p0.x += p1.x; p0.y += p1.y; p0.z += p1.z; p0.w += p1.w;
    q0.x += q1.x; q0.y += q1.y; q0.z += q1.z; q0.w += q1.w;
    r0 = p0;
    r1 = q0;
}

// Fused layer: Hout[n] = relu( (A·Hin)[n] @ W + bias ). One 32-row tile/block.
// W staged in two 64x128 halves; accumulators live across both passes.
// 48 KiB LDS, launch_bounds(512,6): VGPR cap 85 (room for load batching),
// 3 blocks/CU = 24 waves.
__global__ __launch_bounds__(512, 6) void k_layer(
    const float* __restrict__ Hin, const float* __restrict__ W,
    const float* __restrict__ bias,
    const int* __restrict__ rowptr, const float2* __restrict__ csr_pack,
    const float* __restrict__ dinv, int dummy,
    float* __restrict__ Hout, int N)
{
    __shared__ float Wl[64 * 128];    // 32 KiB: half of W [k][c]
    __shared__ float hl[32 * 128];    // 16 KiB: 32 aggregated rows
    const int tid = threadIdx.x;
    for (int i = tid; i < 2048; i += 512)
        ((float4*)Wl)[i] = ((const float4*)W)[i];          // k rows 0..63

    const int lane = tid & 31;
    const int grp  = tid >> 5;        // 0..15
    const int rowBase = blockIdx.x << 5;

    const int n0 = rowBase + grp;
    const int n1 = rowBase + grp + 16;
    const int v0 = n0 < N, v1 = n1 < N;
    float4 g0, g1;
    gather_pair8(n0, n1, v0, v1, Hin, rowptr, csr_pack, dinv, lane, dummy, g0, g1);
    if (v0) *(float4*)(hl + grp * 128 + 4 * lane) = g0;
    if (v1) *(float4*)(hl + (grp + 16) * 128 + 4 * lane) = g1;
    __syncthreads();   // hl + Wl(half 0) ready

    float4 a0 = make_float4(0.f, 0.f, 0.f, 0.f);
    float4 a1 = make_float4(0.f, 0.f, 0.f, 0.f);
    // pass 0: k = 0..63
    #pragma unroll 4
    for (int kq = 0; kq < 16; ++kq) {
        const float4 h0 = *(const float4*)(hl + grp * 128 + 4 * kq);
        const float4 h1 = *(const float4*)(hl + (grp + 16) * 128 + 4 * kq);
        const float4* wp = ((const float4*)Wl) + (4 * kq) * 32 + lane;
        const float4 w0 = wp[0];
        const float4 w1 = wp[32];
        const float4 w2 = wp[64];
        const float4 w3 = wp[96];
        fma4(a0, h0.x, w0); fma4(a0, h0.y, w1); fma4(a0, h0.z, w2); fma4(a0, h0.w, w3);
        fma4(a1, h1.x, w0); fma4(a1, h1.y, w1); fma4(a1, h1.z, w2); fma4(a1, h1.w, w3);
    }
    __syncthreads();   // pass-0 Wl reads done
    for (int i = tid; i < 2048; i += 512)
        ((float4*)Wl)[i] = ((const float4*)(W + 64 * 128))[i];  // k rows 64..127
    __syncthreads();   // Wl(half 1) ready
    // pass 1: k = 64..127
    #pragma unroll 4
    for (int kq = 0; kq < 16; ++kq) {
        const float4 h0 = *(const float4*)(hl + grp * 128 + 64 + 4 * kq);
        const float4 h1 = *(const float4*)(hl + (grp + 16) * 128 + 64 + 4 * kq);
        const float4* wp = ((const float4*)Wl) + (4 * kq) * 32 + lane;
        const float4 w0 = wp[0];
        const float4 w1 = wp[32];
        const float4 w2 = wp[64];
        const float4 w3 = wp[96];
        fma4(a0, h0.x, w0); fma4(a0, h0.y, w1); fma4(a0, h0.z, w2); fma4(a0, h0.w, w3);
        fma4(a1, h1.x, w0); fma4(a1, h1.y, w1); fma4(a1, h1.z, w2); fma4(a1, h1.w, w3);
    }

    const float4 bv = ((const float4*)bias)[lane];
    a0.x += bv.x; a0.y += bv.y; a0.z += bv.z; a0.w += bv.w;
    a1.x += bv.x; a1.y += bv.y; a1.z += bv.z; a1.w += bv.w;
    a0.x = fmaxf(a0.x, 0.f); a0.y = fmaxf(a0.y, 0.f);
    a0.z = fmaxf(a0.z, 0.f); a0.w = fmaxf(a0.w, 0.f);
    a1.x = fmaxf(a1.x, 0.f); a1.y = fmaxf(a1.y, 0.f);
    a1.z = fmaxf(a1.z, 0.f); a1.w = fmaxf(a1.w, 0.f);
    if (v0) *(float4*)(Hout + (size_t)n0 * 128 + 4 * lane) = a0;
    if (v1) *(float4*)(Hout + (size_t)n1 * 128 + 4 * lane) = a1;
}

// Layer 4: pure gather (matvec commuted past the mean-pool), 2 nodes/group
__global__ __launch_bounds__(256, 6) void k_gather4(
    const int* __restrict__ rowptr, const float2* __restrict__ csr_pack,
    const float* __restrict__ dinv, const float* __restrict__ Hin,
    float* __restrict__ outb, int dummy, int N)
{
    const int t = blockIdx.x * blockDim.x + threadIdx.x;
    const int lane = t & 31;
    const int g = t >> 5;
    const int n0 = 2 * g, n1 = 2 * g + 1;
    if (n0 >= N) return;
    float4 r0, r1;
    gather_pair8(n0, n1, 1, n1 < N, Hin, rowptr, csr_pack, dinv, lane, dummy, r0, r1);
    *(float4*)(outb + (size_t)n0 * 128 + 4 * lane) = r0;
    if (n1 < N) *(float4*)(outb + (size_t)n1 * 128 + 4 * lane) = r1;
}

// one block per graph; rows start[g]..start[g+1] contiguous (batch sorted)
__global__ void k_pool_seg(const float* __restrict__ h, const int* __restrict__ start,
                           float* __restrict__ pooled)
{
    __shared__ float4 sh[8][32];
    const int g = blockIdx.x;
    const int t = threadIdx.x;
    const int lane = t & 31, grp = t >> 5;
    const int s0 = start[g], s1 = start[g + 1];

    float4 acc = make_float4(0.f, 0.f, 0.f, 0.f);
    for (int r = s0 + grp; r < s1; r += 8) {
        const float4 v = *(const float4*)(h + (size_t)r * 128 + 4 * lane);
        acc.x += v.x; acc.y += v.y; acc.z += v.z; acc.w += v.w;
    }
    sh[grp][lane] = acc;
    __syncthreads();
    if (grp == 0) {
        float4 a = sh[0][lane];
        #pragma unroll
        for (int k = 1; k < 8; ++k) {
            a.x += sh[k][lane].x; a.y += sh[k][lane].y;
            a.z += sh[k][lane].z; a.w += sh[k][lane].w;
        }
        const float inv = 1.0f / fmaxf((float)(s1 - s0), 1.0f);
        a.x *= inv; a.y *= inv; a.z *= inv; a.w *= inv;
        *(float4*)(pooled + (size_t)g * 128 + 4 * lane) = a;
    }
}

// out[g][t] = pooled[g] . Wc[:,t] + bc[t]
__global__ void k_final(const float* __restrict__ pooled, const float* __restrict__ Wc,
                        const float* __restrict__ bc, float* __restrict__ out, int T)
{
    __shared__ float hv[128];
    const int g = blockIdx.x;
    const int c = threadIdx.x;
    hv[c] = pooled[(size_t)g * 128 + c];
    __syncthreads();
    if (c < T) {
        float acc = bc[c];
        #pragma unroll
        for (int k = 0; k < 128; ++k)
            acc = fmaf(hv[k], Wc[k * T + c], acc);
        out[g * T + c] = acc;
    }
}

extern "C" void kernel_launch(void* const* d_in, const int* in_sizes, int n_in,
                              void* d_out, int out_size, void* d_ws, size_t ws_size,
                              hipStream_t stream)
{
    const float* x     = (const float*)d_in[0];
    const int*   ei    = (const int*)d_in[1];
    const int*   batch = (const int*)d_in[2];
    const float* W1    = (const float*)d_in[3];
    const float* b1    = (const float*)d_in[4];
    const float* Ws    = (const float*)d_in[5];
    const float* bs    = (const float*)d_in[6];
    const float* Wlin  = (const float*)d_in[7];
    const float* blin  = (const float*)d_in[8];
    float* out = (float*)d_out;

    const int N = in_sizes[0] / 128;
    const int E = in_sizes[1] / 2;
    const int T = in_sizes[8];           // 10
    const int G = out_size / T;          // 512

    const int packCap = E + 7 * N + 8;   // padded records + dummy chunk
    const int dummy   = E + 7 * N;       // 8 zero records live here

    // workspace layout (float offsets):
    float*  ws = (float*)d_ws;
    int*    cnt      = (int*)ws;                     // [N] histogram -> cursor (dead after fill)
    int*    rowptr   = (int*)(ws + 50000);           // [N+1]
    int*    bsums    = (int*)(ws + 100016);          // [256]
    int*    start    = (int*)(ws + 100272);          // [G+1]
    float2* csr_pack = (float2*)(ws + 100800);       // [packCap]
    float*  dinv     = ws + 2080832;                 // [N]
    float*  bufA     = ws + 2130832;                 // [N*128]
    float*  bufB     = ws + 8530832;                 // [N*128]
    float*  pooled   = ws + 14930832;                // [G*128]
    float*  Wc       = ws + 24000;                   // reuse cnt region (dead), [128*T]
    float*  bc       = ws + 24000 + 128 * 10;        // [T]

    const int* srcs = ei;
    const int* dsts = ei + E;
    const float* W4 = Ws + 2 * 16384;
    const float* b4 = bs + 2 * 128;

    hipMemsetAsync(cnt, 0, (size_t)N * sizeof(int), stream);
    hipMemsetAsync(csr_pack, 0, (size_t)packCap * sizeof(float2), stream);

    const int nb = (N + 255) / 256;
    k_count <<<(E + 255) / 256, 256, 0, stream>>>(dsts, E, cnt);
    k_scan1 <<<nb, 256, 0, stream>>>(cnt, N, rowptr, bsums, dinv);
    k_scan2 <<<1, 256, 0, stream>>>(bsums, nb);
    k_scan3 <<<nb, 256, 0, stream>>>(rowptr, bsums, cnt, N);
    k_fill  <<<(E + 255) / 256, 256, 0, stream>>>(srcs, dsts, rowptr, cnt, dinv, csr_pack, E);
    k_bounds<<<(G + 256) / 256, 256, 0, stream>>>(batch, N, G, start);
    // cnt region dead from here; Wc/bc overlap it (k_combine runs after k_fill)
    k_combine<<<(128 * T + 255) / 256, 256, 0, stream>>>(W4, Wlin, b4, blin, Wc, bc, T);

    const int layerBlocks = (N + 31) / 32;   // 1563, one 32-row tile each

    k_layer<<<layerBlocks, 512, 0, stream>>>(x,    W1,         b1,       rowptr, csr_pack, dinv, dummy, bufA, N);
    k_layer<<<layerBlocks, 512, 0, stream>>>(bufA, Ws,         bs,       rowptr, csr_pack, dinv, dummy, bufB, N);
    k_layer<<<layerBlocks, 512, 0, stream>>>(bufB, Ws + 16384, bs + 128, rowptr, csr_pack, dinv, dummy, bufA, N);
    // layer 4: gather only
    const int g4blocks = (((N + 1) / 2) * 32 + 255) / 256;
    k_gather4<<<g4blocks, 256, 0, stream>>>(rowptr, csr_pack, dinv, bufA, bufB, dummy, N);

    k_pool_seg<<<G, 256, 0, stream>>>(bufB, start, pooled);
    k_final   <<<G, 128, 0, stream>>>(pooled, Wc, bc, out, T);
}

// Round 11
// 362.509 us; speedup vs baseline: 1.2124x; 1.2124x over previous
//
#include <hip/hip_runtime.h>

// ---------------------------------------------------------------------------
// GCN forward, pull-based + fused. A(HW) = (AH)W:
//   per layer one kernel: gather A·H rows into LDS (branch-free padded CSR,
//   8 independent load chains - r8's proven loop), then 128x128 matvec with
//   W staged in EIGHT 8 KiB chunks. 16 rows/block, 256 threads, 16 KiB LDS
//   -> 8 blocks/CU x 4 waves = 32 waves/CU with natural (uncapped) VGPR.
//   Layer 4's matvec commutes past the mean-pool:
//   out = mean(agg4)·(W4·Wlin) + (b4·Wlin + blin); layer 4 = pure gather,
//   then segmented mean-pool (batch sorted).
// ---------------------------------------------------------------------------

__global__ void k_count(const int* __restrict__ dstv, int E, int* __restrict__ cnt) {
    int e = blockIdx.x * blockDim.x + threadIdx.x;
    if (e < E) atomicAdd(&cnt[dstv[e]], 1);
}

// scan over PADDED counts ((deg+3)&~3); also emits dinv from raw deg
__global__ void k_scan1(const int* __restrict__ cnt, int N,
                        int* __restrict__ rowptr, int* __restrict__ bsums,
                        float* __restrict__ dinv) {
    __shared__ int sh[256];
    const int t = threadIdx.x;
    const int i = blockIdx.x * 256 + t;
    const int v = (i < N) ? cnt[i] : 0;
    const int pv = (v + 3) & ~3;
    if (i < N) dinv[i] = 1.0f / sqrtf((float)(v + 1));  // +1 self loop
    sh[t] = pv;
    __syncthreads();
    for (int off = 1; off < 256; off <<= 1) {
        int add = (t >= off) ? sh[t - off] : 0;
        __syncthreads();
        sh[t] += add;
        __syncthreads();
    }
    if (i < N) rowptr[i] = sh[t] - pv;
    if (t == 255) bsums[blockIdx.x] = sh[255];
}

__global__ void k_scan2(int* __restrict__ bsums, int nb) {
    __shared__ int sh[256];
    const int t = threadIdx.x;
    const int v = (t < nb) ? bsums[t] : 0;
    sh[t] = v;
    __syncthreads();
    for (int off = 1; off < 256; off <<= 1) {
        int add = (t >= off) ? sh[t - off] : 0;
        __syncthreads();
        sh[t] += add;
        __syncthreads();
    }
    if (t < nb) bsums[t] = sh[t] - v;
}

__global__ void k_scan3(int* __restrict__ rowptr, const int* __restrict__ bsums,
                        int* __restrict__ cnt, int N) {
    const int i = blockIdx.x * blockDim.x + threadIdx.x;
    if (i < N) {
        rowptr[i] += bsums[i >> 8];
        if (i == N - 1) rowptr[N] = rowptr[i] + ((cnt[i] + 3) & ~3);
        cnt[i] = 0;                            // becomes fill cursor
    }
}

// packed edge record: .x = src index (bit pattern), .y = dinv[src]*dinv[dst]
// pad slots (memset to 0) = {src 0, weight 0.0}
__global__ void k_fill(const int* __restrict__ srcv, const int* __restrict__ dstv,
                       const int* __restrict__ rowptr, int* __restrict__ cur,
                       const float* __restrict__ dinv,
                       float2* __restrict__ csr_pack, int E) {
    int e = blockIdx.x * blockDim.x + threadIdx.x;
    if (e < E) {
        const int d = dstv[e];
        const int s = srcv[e];
        const int slot = atomicAdd(&cur[d], 1);
        float2 rec;
        rec.x = __int_as_float(s);
        rec.y = dinv[s] * dinv[d];
        csr_pack[rowptr[d] + slot] = rec;
    }
}

__global__ void k_bounds(const int* __restrict__ batch, int N, int G,
                         int* __restrict__ start) {
    const int g = blockIdx.x * blockDim.x + threadIdx.x;
    if (g > G) return;
    int lo = 0, hi = N;
    while (lo < hi) {
        const int mid = (lo + hi) >> 1;
        if (batch[mid] < g) lo = mid + 1; else hi = mid;
    }
    start[g] = lo;
}

// Wc = W4 @ Wlin (128 x T), bc = b4 @ Wlin + blin (T)
__global__ void k_combine(const float* __restrict__ W4, const float* __restrict__ Wlin,
                          const float* __restrict__ b4, const float* __restrict__ blin,
                          float* __restrict__ Wc, float* __restrict__ bc, int T) {
    const int idx = blockIdx.x * blockDim.x + threadIdx.x;
    if (idx < 128 * T) {
        const int k = idx / T, t = idx % T;
        float acc = 0.f;
        #pragma unroll 8
        for (int j = 0; j < 128; ++j)
            acc = fmaf(W4[k * 128 + j], Wlin[j * T + t], acc);
        Wc[idx] = acc;
    }
    if (idx < T) {
        float acc = blin[idx];
        #pragma unroll 8
        for (int j = 0; j < 128; ++j)
            acc = fmaf(b4[j], Wlin[j * T + idx], acc);
        bc[idx] = acc;
    }
}

__device__ __forceinline__ void fma4(float4& acc, float s, const float4& w) {
    acc.x = fmaf(s, w.x, acc.x);
    acc.y = fmaf(s, w.y, acc.y);
    acc.z = fmaf(s, w.z, acc.z);
    acc.w = fmaf(s, w.w, acc.w);
}

// Gather aggregated rows n0 AND n1, interleaved 4-wide each: 8 independent
// {record -> row} load chains. Branch-free body: rows padded to x4 records,
// exhausted rows redirect their CHUNK ADDRESS to the dummy zero-chunk.
// (r8's proven inner loop, verbatim.)
__device__ __forceinline__ void gather_pair2(
    int n0, int n1, int v0, int v1,
    const float* __restrict__ Hin,
    const int* __restrict__ rowptr, const float2* __restrict__ pk,
    const float* __restrict__ dinv, int lane, int dummy,
    float4& r0, float4& r1)
{
    const int nc0 = v0 ? n0 : 0;
    const int nc1 = v1 ? n1 : 0;
    const float dn0 = v0 ? dinv[nc0] : 0.f;
    const float dn1 = v1 ? dinv[nc1] : 0.f;
    int c0 = rowptr[nc0];
    int c1 = rowptr[nc1];
    const int e0 = v0 ? rowptr[nc0 + 1] : c0;
    const int e1 = v1 ? rowptr[nc1 + 1] : c1;

    const float4 s0v = *(const float4*)(Hin + (size_t)nc0 * 128 + 4 * lane);
    const float4 s1v = *(const float4*)(Hin + (size_t)nc1 * 128 + 4 * lane);
    const float sw0 = dn0 * dn0, sw1 = dn1 * dn1;
    float4 p0 = make_float4(s0v.x * sw0, s0v.y * sw0, s0v.z * sw0, s0v.w * sw0);
    float4 q0 = make_float4(s1v.x * sw1, s1v.y * sw1, s1v.z * sw1, s1v.w * sw1);
    float4 p1 = make_float4(0.f, 0.f, 0.f, 0.f);
    float4 q1 = make_float4(0.f, 0.f, 0.f, 0.f);

    while (c0 < e0 || c1 < e1) {
        const int a0 = (c0 < e0) ? c0 : dummy;   // chunk-level select only
        const int a1 = (c1 < e1) ? c1 : dummy;
        const float2 ra0 = pk[a0];
        const float2 ra1 = pk[a0 + 1];
        const float2 ra2 = pk[a0 + 2];
        const float2 ra3 = pk[a0 + 3];
        const float2 rb0 = pk[a1];
        const float2 rb1 = pk[a1 + 1];
        const float2 rb2 = pk[a1 + 2];
        const float2 rb3 = pk[a1 + 3];
        const float4 va0 = *(const float4*)(Hin + (size_t)__float_as_int(ra0.x) * 128 + 4 * lane);
        const float4 va1 = *(const float4*)(Hin + (size_t)__float_as_int(ra1.x) * 128 + 4 * lane);
        const float4 va2 = *(const float4*)(Hin + (size_t)__float_as_int(ra2.x) * 128 + 4 * lane);
        const float4 va3 = *(const float4*)(Hin + (size_t)__float_as_int(ra3.x) * 128 + 4 * lane);
        const float4 vb0 = *(const float4*)(Hin + (size_t)__float_as_int(rb0.x) * 128 + 4 * lane);
        const float4 vb1 = *(const float4*)(Hin + (size_t)__float_as_int(rb1.x) * 128 + 4 * lane);
        const float4 vb2 = *(const float4*)(Hin + (size_t)__float_as_int(rb2.x) * 128 + 4 * lane);
        const float4 vb3 = *(const float4*)(Hin + (size_t)__float_as_int(rb3.x) * 128 + 4 * lane);
        fma4(p0, ra0.y, va0); fma4(p1, ra1.y, va1);
        fma4(p0, ra2.y, va2); fma4(p1, ra3.y, va3);
        fma4(q0, rb0.y, vb0); fma4(q1, rb1.y, vb1);
        fma4(q0, rb2.y, vb2); fma4(q1, rb3.y, vb3);
        c0 += 4; c1 += 4;
    }
    p0.x += p1.x; p0.y += p1.y; p0.z += p1.z; p0.w += p1.w;
    q0.x += q1.x; q0.y += q1.y; q0.z += q1.z; q0.w += q1.w;
    r0 = p0;
    r1 = q0;
}

// Fused layer: Hout[n] = relu( (A·Hin)[n] @ W + bias ). One 16-row tile/block,
// 256 threads. W staged in eight 16x128 chunks (8 KiB); hl 8 KiB -> LDS
// 16 KiB/block -> 8 blocks/CU x 4 waves = 32 waves/CU at natural VGPR.
__global__ __launch_bounds__(256) void k_layer(
    const float* __restrict__ Hin, const float* __restrict__ W,
    const float* __restrict__ bias,
    const int* __restrict__ rowptr, const float2* __restrict__ csr_pack,
    const float* __restrict__ dinv, int dummy,
    float* __restrict__ Hout, int N)
{
    __shared__ float Wl[16 * 128];    // 8 KiB: chunk of W [k][c]
    __shared__ float hl[16 * 128];    // 8 KiB: 16 aggregated rows
    const int tid = threadIdx.x;
    for (int i = tid; i < 512; i += 256)
        ((float4*)Wl)[i] = ((const float4*)W)[i];          // k rows 0..15

    const int lane = tid & 31;
    const int grp  = tid >> 5;        // 0..7
    const int rowBase = blockIdx.x << 4;

    const int n0 = rowBase + grp;
    const int n1 = rowBase + grp + 8;
    const int v0 = n0 < N, v1 = n1 < N;
    float4 g0, g1;
    gather_pair2(n0, n1, v0, v1, Hin, rowptr, csr_pack, dinv, lane, dummy, g0, g1);
    if (v0) *(float4*)(hl + grp * 128 + 4 * lane) = g0;
    if (v1) *(float4*)(hl + (grp + 8) * 128 + 4 * lane) = g1;
    __syncthreads();   // hl + Wl(chunk 0) ready

    float4 a0 = make_float4(0.f, 0.f, 0.f, 0.f);
    float4 a1 = make_float4(0.f, 0.f, 0.f, 0.f);
    for (int p = 0; p < 8; ++p) {
        if (p > 0) {
            __syncthreads();   // chunk p-1 Wl reads done
            for (int i = tid; i < 512; i += 256)
                ((float4*)Wl)[i] = ((const float4*)(W + p * 2048))[i];
            __syncthreads();   // Wl(chunk p) ready
        }
        #pragma unroll
        for (int kq = 0; kq < 4; ++kq) {
            const float4 h0 = *(const float4*)(hl + grp * 128 + 16 * p + 4 * kq);
            const float4 h1 = *(const float4*)(hl + (grp + 8) * 128 + 16 * p + 4 * kq);
            const float4* wp = ((const float4*)Wl) + (4 * kq) * 32 + lane;
            const float4 w0 = wp[0];
            const float4 w1 = wp[32];
            const float4 w2 = wp[64];
            const float4 w3 = wp[96];
            fma4(a0, h0.x, w0); fma4(a0, h0.y, w1); fma4(a0, h0.z, w2); fma4(a0, h0.w, w3);
            fma4(a1, h1.x, w0); fma4(a1, h1.y, w1); fma4(a1, h1.z, w2); fma4(a1, h1.w, w3);
        }
    }

    const float4 bv = ((const float4*)bias)[lane];
    a0.x += bv.x; a0.y += bv.y; a0.z += bv.z; a0.w += bv.w;
    a1.x += bv.x; a1.y += bv.y; a1.z += bv.z; a1.w += bv.w;
    a0.x = fmaxf(a0.x, 0.f); a0.y = fmaxf(a0.y, 0.f);
    a0.z = fmaxf(a0.z, 0.f); a0.w = fmaxf(a0.w, 0.f);
    a1.x = fmaxf(a1.x, 0.f); a1.y = fmaxf(a1.y, 0.f);
    a1.z = fmaxf(a1.z, 0.f); a1.w = fmaxf(a1.w, 0.f);
    if (v0) *(float4*)(Hout + (size_t)n0 * 128 + 4 * lane) = a0;
    if (v1) *(float4*)(Hout + (size_t)n1 * 128 + 4 * lane) = a1;
}

// Layer 4: pure gather (matvec commuted past the mean-pool), adjacent pair
__global__ __launch_bounds__(256) void k_gather4(
    const int* __restrict__ rowptr, const float2* __restrict__ csr_pack,
    const float* __restrict__ dinv, const float* __restrict__ Hin,
    float* __restrict__ outb, int dummy, int N)
{
    const int t = blockIdx.x * blockDim.x + threadIdx.x;
    const int lane = t & 31;
    const int g = t >> 5;
    const int n0 = 2 * g, n1 = 2 * g + 1;
    if (n0 >= N) return;
    float4 r0, r1;
    gather_pair2(n0, n1, 1, n1 < N, Hin, rowptr, csr_pack, dinv, lane, dummy, r0, r1);
    *(float4*)(outb + (size_t)n0 * 128 + 4 * lane) = r0;
    if (n1 < N) *(float4*)(outb + (size_t)n1 * 128 + 4 * lane) = r1;
}

// one block per graph; rows start[g]..start[g+1] contiguous (batch sorted)
__global__ void k_pool_seg(const float* __restrict__ h, const int* __restrict__ start,
                           float* __restrict__ pooled)
{
    __shared__ float4 sh[8][32];
    const int g = blockIdx.x;
    const int t = threadIdx.x;
    const int lane = t & 31, grp = t >> 5;
    const int s0 = start[g], s1 = start[g + 1];

    float4 acc = make_float4(0.f, 0.f, 0.f, 0.f);
    for (int r = s0 + grp; r < s1; r += 8) {
        const float4 v = *(const float4*)(h + (size_t)r * 128 + 4 * lane);
        acc.x += v.x; acc.y += v.y; acc.z += v.z; acc.w += v.w;
    }
    sh[grp][lane] = acc;
    __syncthreads();
    if (grp == 0) {
        float4 a = sh[0][lane];
        #pragma unroll
        for (int k = 1; k < 8; ++k) {
            a.x += sh[k][lane].x; a.y += sh[k][lane].y;
            a.z += sh[k][lane].z; a.w += sh[k][lane].w;
        }
        const float inv = 1.0f / fmaxf((float)(s1 - s0), 1.0f);
        a.x *= inv; a.y *= inv; a.z *= inv; a.w *= inv;
        *(float4*)(pooled + (size_t)g * 128 + 4 * lane) = a;
    }
}

// out[g][t] = pooled[g] . Wc[:,t] + bc[t]
__global__ void k_final(const float* __restrict__ pooled, const float* __restrict__ Wc,
                        const float* __restrict__ bc, float* __restrict__ out, int T)
{
    __shared__ float hv[128];
    const int g = blockIdx.x;
    const int c = threadIdx.x;
    hv[c] = pooled[(size_t)g * 128 + c];
    __syncthreads();
    if (c < T) {
        float acc = bc[c];
        #pragma unroll
        for (int k = 0; k < 128; ++k)
            acc = fmaf(hv[k], Wc[k * T + c], acc);
        out[g * T + c] = acc;
    }
}

extern "C" void kernel_launch(void* const* d_in, const int* in_sizes, int n_in,
                              void* d_out, int out_size, void* d_ws, size_t ws_size,
                              hipStream_t stream)
{
    const float* x     = (const float*)d_in[0];
    const int*   ei    = (const int*)d_in[1];
    const int*   batch = (const int*)d_in[2];
    const float* W1    = (const float*)d_in[3];
    const float* b1    = (const float*)d_in[4];
    const float* Ws    = (const float*)d_in[5];
    const float* bs    = (const float*)d_in[6];
    const float* Wlin  = (const float*)d_in[7];
    const float* blin  = (const float*)d_in[8];
    float* out = (float*)d_out;

    const int N = in_sizes[0] / 128;
    const int E = in_sizes[1] / 2;
    const int T = in_sizes[8];           // 10
    const int G = out_size / T;          // 512

    const int packCap = E + 3 * N + 4;   // padded records + dummy chunk
    const int dummy   = E + 3 * N;       // 4 zero records live here

    // workspace layout (float offsets):
    float*  ws = (float*)d_ws;
    int*    cnt      = (int*)ws;                     // [N] histogram -> cursor (dead after fill)
    int*    rowptr   = (int*)(ws + 50000);           // [N+1]
    int*    bsums    = (int*)(ws + 100016);          // [256]
    int*    start    = (int*)(ws + 100272);          // [G+1]
    float2* csr_pack = (float2*)(ws + 100800);       // [packCap]
    float*  dinv     = ws + 1680816;                 // [N]
    float*  bufA     = ws + 1730816;                 // [N*128]
    float*  bufB     = ws + 8130816;                 // [N*128]
    float*  pooled   = ws + 14530816;                // [G*128]
    float*  Wc       = ws + 24000;                   // reuse cnt region (dead), [128*T]
    float*  bc       = ws + 24000 + 128 * 10;        // [T]

    const int* srcs = ei;
    const int* dsts = ei + E;
    const float* W4 = Ws + 2 * 16384;
    const float* b4 = bs + 2 * 128;

    hipMemsetAsync(cnt, 0, (size_t)N * sizeof(int), stream);
    hipMemsetAsync(csr_pack, 0, (size_t)packCap * sizeof(float2), stream);

    const int nb = (N + 255) / 256;
    k_count <<<(E + 255) / 256, 256, 0, stream>>>(dsts, E, cnt);
    k_scan1 <<<nb, 256, 0, stream>>>(cnt, N, rowptr, bsums, dinv);
    k_scan2 <<<1, 256, 0, stream>>>(bsums, nb);
    k_scan3 <<<nb, 256, 0, stream>>>(rowptr, bsums, cnt, N);
    k_fill  <<<(E + 255) / 256, 256, 0, stream>>>(srcs, dsts, rowptr, cnt, dinv, csr_pack, E);
    k_bounds<<<(G + 256) / 256, 256, 0, stream>>>(batch, N, G, start);
    // cnt region dead from here; Wc/bc overlap it (k_combine runs after k_fill)
    k_combine<<<(128 * T + 255) / 256, 256, 0, stream>>>(W4, Wlin, b4, blin, Wc, bc, T);

    const int layerBlocks = (N + 15) / 16;   // 3125, one 16-row tile each

    k_layer<<<layerBlocks, 256, 0, stream>>>(x,    W1,         b1,       rowptr, csr_pack, dinv, dummy, bufA, N);
    k_layer<<<layerBlocks, 256, 0, stream>>>(bufA, Ws,         bs,       rowptr, csr_pack, dinv, dummy, bufB, N);
    k_layer<<<layerBlocks, 256, 0, stream>>>(bufB, Ws + 16384, bs + 128, rowptr, csr_pack, dinv, dummy, bufA, N);
    // layer 4: gather only
    const int g4blocks = (((N + 1) / 2) * 32 + 255) / 256;
    k_gather4<<<g4blocks, 256, 0, stream>>>(rowptr, csr_pack, dinv, bufA, bufB, dummy, N);

    k_pool_seg<<<G, 256, 0, stream>>>(bufB, start, pooled);
    k_final   <<<G, 128, 0, stream>>>(pooled, Wc, bc, out, T);
}

// Round 12
// 288.886 us; speedup vs baseline: 1.5214x; 1.2549x over previous
//
#include <hip/hip_runtime.h>
#include <hip/hip_fp16.h>

// ---------------------------------------------------------------------------
// GCN forward, pull-based + fused. A(HW) = (AH)W:
//   per layer one kernel: gather A·H rows into LDS (branch-free padded CSR,
//   8 independent load chains - r8's proven loop), then 128x128 matvec with
//   W staged in two 32 KiB halves (48 KiB LDS -> 3 blocks/CU at 512 thr).
//   NEW: inter-layer H buffers stored fp16 (256 B/row) -> gather traffic
//   halves; all arithmetic stays fp32. Layer 4's matvec commutes past the
//   mean-pool: out = mean(agg4)·(W4·Wlin) + (b4·Wlin + blin).
// ---------------------------------------------------------------------------

__global__ void k_count(const int* __restrict__ dstv, int E, int* __restrict__ cnt) {
    int e = blockIdx.x * blockDim.x + threadIdx.x;
    if (e < E) atomicAdd(&cnt[dstv[e]], 1);
}

// scan over PADDED counts ((deg+3)&~3); also emits dinv from raw deg
__global__ void k_scan1(const int* __restrict__ cnt, int N,
                        int* __restrict__ rowptr, int* __restrict__ bsums,
                        float* __restrict__ dinv) {
    __shared__ int sh[256];
    const int t = threadIdx.x;
    const int i = blockIdx.x * 256 + t;
    const int v = (i < N) ? cnt[i] : 0;
    const int pv = (v + 3) & ~3;
    if (i < N) dinv[i] = 1.0f / sqrtf((float)(v + 1));  // +1 self loop
    sh[t] = pv;
    __syncthreads();
    for (int off = 1; off < 256; off <<= 1) {
        int add = (t >= off) ? sh[t - off] : 0;
        __syncthreads();
        sh[t] += add;
        __syncthreads();
    }
    if (i < N) rowptr[i] = sh[t] - pv;
    if (t == 255) bsums[blockIdx.x] = sh[255];
}

__global__ void k_scan2(int* __restrict__ bsums, int nb) {
    __shared__ int sh[256];
    const int t = threadIdx.x;
    const int v = (t < nb) ? bsums[t] : 0;
    sh[t] = v;
    __syncthreads();
    for (int off = 1; off < 256; off <<= 1) {
        int add = (t >= off) ? sh[t - off] : 0;
        __syncthreads();
        sh[t] += add;
        __syncthreads();
    }
    if (t < nb) bsums[t] = sh[t] - v;
}

__global__ void k_scan3(int* __restrict__ rowptr, const int* __restrict__ bsums,
                        int* __restrict__ cnt, int N) {
    const int i = blockIdx.x * blockDim.x + threadIdx.x;
    if (i < N) {
        rowptr[i] += bsums[i >> 8];
        if (i == N - 1) rowptr[N] = rowptr[i] + ((cnt[i] + 3) & ~3);
        cnt[i] = 0;                            // becomes fill cursor
    }
}

// packed edge record: .x = src index (bit pattern), .y = dinv[src]*dinv[dst]
// pad slots (memset to 0) = {src 0, weight 0.0}
__global__ void k_fill(const int* __restrict__ srcv, const int* __restrict__ dstv,
                       const int* __restrict__ rowptr, int* __restrict__ cur,
                       const float* __restrict__ dinv,
                       float2* __restrict__ csr_pack, int E) {
    int e = blockIdx.x * blockDim.x + threadIdx.x;
    if (e < E) {
        const int d = dstv[e];
        const int s = srcv[e];
        const int slot = atomicAdd(&cur[d], 1);
        float2 rec;
        rec.x = __int_as_float(s);
        rec.y = dinv[s] * dinv[d];
        csr_pack[rowptr[d] + slot] = rec;
    }
}

__global__ void k_bounds(const int* __restrict__ batch, int N, int G,
                         int* __restrict__ start) {
    const int g = blockIdx.x * blockDim.x + threadIdx.x;
    if (g > G) return;
    int lo = 0, hi = N;
    while (lo < hi) {
        const int mid = (lo + hi) >> 1;
        if (batch[mid] < g) lo = mid + 1; else hi = mid;
    }
    start[g] = lo;
}

// Wc = W4 @ Wlin (128 x T), bc = b4 @ Wlin + blin (T)
__global__ void k_combine(const float* __restrict__ W4, const float* __restrict__ Wlin,
                          const float* __restrict__ b4, const float* __restrict__ blin,
                          float* __restrict__ Wc, float* __restrict__ bc, int T) {
    const int idx = blockIdx.x * blockDim.x + threadIdx.x;
    if (idx < 128 * T) {
        const int k = idx / T, t = idx % T;
        float acc = 0.f;
        #pragma unroll 8
        for (int j = 0; j < 128; ++j)
            acc = fmaf(W4[k * 128 + j], Wlin[j * T + t], acc);
        Wc[idx] = acc;
    }
    if (idx < T) {
        float acc = blin[idx];
        #pragma unroll 8
        for (int j = 0; j < 128; ++j)
            acc = fmaf(b4[j], Wlin[j * T + idx], acc);
        bc[idx] = acc;
    }
}

__device__ __forceinline__ void fma4(float4& acc, float s, const float4& w) {
    acc.x = fmaf(s, w.x, acc.x);
    acc.y = fmaf(s, w.y, acc.y);
    acc.z = fmaf(s, w.z, acc.z);
    acc.w = fmaf(s, w.w, acc.w);
}

// load 4 consecutive halves as float4 (one 8B vmem load + 2 cvt)
__device__ __forceinline__ float4 ld_h4(const __half* p) {
    const float2 raw = *(const float2*)p;
    const __half2* hp = (const __half2*)&raw;
    const float2 f01 = __half22float2(hp[0]);
    const float2 f23 = __half22float2(hp[1]);
    return make_float4(f01.x, f01.y, f23.x, f23.y);
}

// store float4 as 4 halves (8B)
__device__ __forceinline__ void st_h4(__half* p, float4 v) {
    float2 raw;
    ((__half2*)&raw)[0] = __floats2half2_rn(v.x, v.y);
    ((__half2*)&raw)[1] = __floats2half2_rn(v.z, v.w);
    *(float2*)p = raw;
}

// x (fp32) -> x16 (fp16), 4 elements/thread
__global__ void k_cvt(const float* __restrict__ in, __half* __restrict__ out, int n4) {
    int i = blockIdx.x * blockDim.x + threadIdx.x;
    if (i < n4) {
        const float4 v = ((const float4*)in)[i];
        st_h4(out + 4 * i, v);
    }
}

// Gather aggregated rows n0 AND n1 from fp16 H, interleaved 4-wide each:
// 8 independent {record -> row} load chains. Branch-free body: rows padded
// to x4 records, exhausted rows redirect their CHUNK ADDRESS to the dummy
// zero-chunk. (r8's proven structure, fp16 row payloads.)
__device__ __forceinline__ void gather_pair2(
    int n0, int n1, int v0, int v1,
    const __half* __restrict__ Hin,
    const int* __restrict__ rowptr, const float2* __restrict__ pk,
    const float* __restrict__ dinv, int lane, int dummy,
    float4& r0, float4& r1)
{
    const int nc0 = v0 ? n0 : 0;
    const int nc1 = v1 ? n1 : 0;
    const float dn0 = v0 ? dinv[nc0] : 0.f;
    const float dn1 = v1 ? dinv[nc1] : 0.f;
    int c0 = rowptr[nc0];
    int c1 = rowptr[nc1];
    const int e0 = v0 ? rowptr[nc0 + 1] : c0;
    const int e1 = v1 ? rowptr[nc1 + 1] : c1;

    const float4 s0v = ld_h4(Hin + (size_t)nc0 * 128 + 4 * lane);
    const float4 s1v = ld_h4(Hin + (size_t)nc1 * 128 + 4 * lane);
    const float sw0 = dn0 * dn0, sw1 = dn1 * dn1;
    float4 p0 = make_float4(s0v.x * sw0, s0v.y * sw0, s0v.z * sw0, s0v.w * sw0);
    float4 q0 = make_float4(s1v.x * sw1, s1v.y * sw1, s1v.z * sw1, s1v.w * sw1);
    float4 p1 = make_float4(0.f, 0.f, 0.f, 0.f);
    float4 q1 = make_float4(0.f, 0.f, 0.f, 0.f);

    while (c0 < e0 || c1 < e1) {
        const int a0 = (c0 < e0) ? c0 : dummy;   // chunk-level select only
        const int a1 = (c1 < e1) ? c1 : dummy;
        const float2 ra0 = pk[a0];
        const float2 ra1 = pk[a0 + 1];
        const float2 ra2 = pk[a0 + 2];
        const float2 ra3 = pk[a0 + 3];
        const float2 rb0 = pk[a1];
        const float2 rb1 = pk[a1 + 1];
        const float2 rb2 = pk[a1 + 2];
        const float2 rb3 = pk[a1 + 3];
        const float4 va0 = ld_h4(Hin + (size_t)__float_as_int(ra0.x) * 128 + 4 * lane);
        const float4 va1 = ld_h4(Hin + (size_t)__float_as_int(ra1.x) * 128 + 4 * lane);
        const float4 va2 = ld_h4(Hin + (size_t)__float_as_int(ra2.x) * 128 + 4 * lane);
        const float4 va3 = ld_h4(Hin + (size_t)__float_as_int(ra3.x) * 128 + 4 * lane);
        const float4 vb0 = ld_h4(Hin + (size_t)__float_as_int(rb0.x) * 128 + 4 * lane);
        const float4 vb1 = ld_h4(Hin + (size_t)__float_as_int(rb1.x) * 128 + 4 * lane);
        const float4 vb2 = ld_h4(Hin + (size_t)__float_as_int(rb2.x) * 128 + 4 * lane);
        const float4 vb3 = ld_h4(Hin + (size_t)__float_as_int(rb3.x) * 128 + 4 * lane);
        fma4(p0, ra0.y, va0); fma4(p1, ra1.y, va1);
        fma4(p0, ra2.y, va2); fma4(p1, ra3.y, va3);
        fma4(q0, rb0.y, vb0); fma4(q1, rb1.y, vb1);
        fma4(q0, rb2.y, vb2); fma4(q1, rb3.y, vb3);
        c0 += 4; c1 += 4;
    }
    p0.x += p1.x; p0.y += p1.y; p0.z += p1.z; p0.w += p1.w;
    q0.x += q1.x; q0.y += q1.y; q0.z += q1.z; q0.w += q1.w;
    r0 = p0;
    r1 = q0;
}

// Fused layer: Hout[n] = fp16( relu( (A·Hin)[n] @ W + bias ) ).
// One 32-row tile/block. W staged in two 64x128 halves; accumulators live
// across both passes. 48 KiB LDS, launch_bounds(512,6).
__global__ __launch_bounds__(512, 6) void k_layer(
    const __half* __restrict__ Hin, const float* __restrict__ W,
    const float* __restrict__ bias,
    const int* __restrict__ rowptr, const float2* __restrict__ csr_pack,
    const float* __restrict__ dinv, int dummy,
    __half* __restrict__ Hout, int N)
{
    __shared__ float Wl[64 * 128];    // 32 KiB: half of W [k][c]
    __shared__ float hl[32 * 128];    // 16 KiB: 32 aggregated rows (fp32)
    const int tid = threadIdx.x;
    for (int i = tid; i < 2048; i += 512)
        ((float4*)Wl)[i] = ((const float4*)W)[i];          // k rows 0..63

    const int lane = tid & 31;
    const int grp  = tid >> 5;        // 0..15
    const int rowBase = blockIdx.x << 5;

    const int n0 = rowBase + grp;
    const int n1 = rowBase + grp + 16;
    const int v0 = n0 < N, v1 = n1 < N;
    float4 g0, g1;
    gather_pair2(n0, n1, v0, v1, Hin, rowptr, csr_pack, dinv, lane, dummy, g0, g1);
    if (v0) *(float4*)(hl + grp * 128 + 4 * lane) = g0;
    if (v1) *(float4*)(hl + (grp + 16) * 128 + 4 * lane) = g1;
    __syncthreads();   // hl + Wl(half 0) ready

    float4 a0 = make_float4(0.f, 0.f, 0.f, 0.f);
    float4 a1 = make_float4(0.f, 0.f, 0.f, 0.f);
    // pass 0: k = 0..63
    #pragma unroll 4
    for (int kq = 0; kq < 16; ++kq) {
        const float4 h0 = *(const float4*)(hl + grp * 128 + 4 * kq);
        const float4 h1 = *(const float4*)(hl + (grp + 16) * 128 + 4 * kq);
        const float4* wp = ((const float4*)Wl) + (4 * kq) * 32 + lane;
        const float4 w0 = wp[0];
        const float4 w1 = wp[32];
        const float4 w2 = wp[64];
        const float4 w3 = wp[96];
        fma4(a0, h0.x, w0); fma4(a0, h0.y, w1); fma4(a0, h0.z, w2); fma4(a0, h0.w, w3);
        fma4(a1, h1.x, w0); fma4(a1, h1.y, w1); fma4(a1, h1.z, w2); fma4(a1, h1.w, w3);
    }
    __syncthreads();   // pass-0 Wl reads done
    for (int i = tid; i < 2048; i += 512)
        ((float4*)Wl)[i] = ((const float4*)(W + 64 * 128))[i];  // k rows 64..127
    __syncthreads();   // Wl(half 1) ready
    // pass 1: k = 64..127
    #pragma unroll 4
    for (int kq = 0; kq < 16; ++kq) {
        const float4 h0 = *(const float4*)(hl + grp * 128 + 64 + 4 * kq);
        const float4 h1 = *(const float4*)(hl + (grp + 16) * 128 + 64 + 4 * kq);
        const float4* wp = ((const float4*)Wl) + (4 * kq) * 32 + lane;
        const float4 w0 = wp[0];
        const float4 w1 = wp[32];
        const float4 w2 = wp[64];
        const float4 w3 = wp[96];
        fma4(a0, h0.x, w0); fma4(a0, h0.y, w1); fma4(a0, h0.z, w2); fma4(a0, h0.w, w3);
        fma4(a1, h1.x, w0); fma4(a1, h1.y, w1); fma4(a1, h1.z, w2); fma4(a1, h1.w, w3);
    }

    const float4 bv = ((const float4*)bias)[lane];
    a0.x += bv.x; a0.y += bv.y; a0.z += bv.z; a0.w += bv.w;
    a1.x += bv.x; a1.y += bv.y; a1.z += bv.z; a1.w += bv.w;
    a0.x = fmaxf(a0.x, 0.f); a0.y = fmaxf(a0.y, 0.f);
    a0.z = fmaxf(a0.z, 0.f); a0.w = fmaxf(a0.w, 0.f);
    a1.x = fmaxf(a1.x, 0.f); a1.y = fmaxf(a1.y, 0.f);
    a1.z = fmaxf(a1.z, 0.f); a1.w = fmaxf(a1.w, 0.f);
    if (v0) st_h4(Hout + (size_t)n0 * 128 + 4 * lane, a0);
    if (v1) st_h4(Hout + (size_t)n1 * 128 + 4 * lane, a1);
}

// Layer 4: pure gather (matvec commuted past the mean-pool), adjacent pair,
// fp16 in -> fp16 out (pool accumulates fp32)
__global__ __launch_bounds__(256) void k_gather4(
    const int* __restrict__ rowptr, const float2* __restrict__ csr_pack,
    const float* __restrict__ dinv, const __half* __restrict__ Hin,
    __half* __restrict__ outb, int dummy, int N)
{
    const int t = blockIdx.x * blockDim.x + threadIdx.x;
    const int lane = t & 31;
    const int g = t >> 5;
    const int n0 = 2 * g, n1 = 2 * g + 1;
    if (n0 >= N) return;
    float4 r0, r1;
    gather_pair2(n0, n1, 1, n1 < N, Hin, rowptr, csr_pack, dinv, lane, dummy, r0, r1);
    st_h4(outb + (size_t)n0 * 128 + 4 * lane, r0);
    if (n1 < N) st_h4(outb + (size_t)n1 * 128 + 4 * lane, r1);
}

// one block per graph; rows start[g]..start[g+1] contiguous (batch sorted)
__global__ void k_pool_seg(const __half* __restrict__ h, const int* __restrict__ start,
                           float* __restrict__ pooled)
{
    __shared__ float4 sh[8][32];
    const int g = blockIdx.x;
    const int t = threadIdx.x;
    const int lane = t & 31, grp = t >> 5;
    const int s0 = start[g], s1 = start[g + 1];

    float4 acc = make_float4(0.f, 0.f, 0.f, 0.f);
    for (int r = s0 + grp; r < s1; r += 8) {
        const float4 v = ld_h4(h + (size_t)r * 128 + 4 * lane);
        acc.x += v.x; acc.y += v.y; acc.z += v.z; acc.w += v.w;
    }
    sh[grp][lane] = acc;
    __syncthreads();
    if (grp == 0) {
        float4 a = sh[0][lane];
        #pragma unroll
        for (int k = 1; k < 8; ++k) {
            a.x += sh[k][lane].x; a.y += sh[k][lane].y;
            a.z += sh[k][lane].z; a.w += sh[k][lane].w;
        }
        const float inv = 1.0f / fmaxf((float)(s1 - s0), 1.0f);
        a.x *= inv; a.y *= inv; a.z *= inv; a.w *= inv;
        *(float4*)(pooled + (size_t)g * 128 + 4 * lane) = a;
    }
}

// out[g][t] = pooled[g] . Wc[:,t] + bc[t]
__global__ void k_final(const float* __restrict__ pooled, const float* __restrict__ Wc,
                        const float* __restrict__ bc, float* __restrict__ out, int T)
{
    __shared__ float hv[128];
    const int g = blockIdx.x;
    const int c = threadIdx.x;
    hv[c] = pooled[(size_t)g * 128 + c];
    __syncthreads();
    if (c < T) {
        float acc = bc[c];
        #pragma unroll
        for (int k = 0; k < 128; ++k)
            acc = fmaf(hv[k], Wc[k * T + c], acc);
        out[g * T + c] = acc;
    }
}

extern "C" void kernel_launch(void* const* d_in, const int* in_sizes, int n_in,
                              void* d_out, int out_size, void* d_ws, size_t ws_size,
                              hipStream_t stream)
{
    const float* x     = (const float*)d_in[0];
    const int*   ei    = (const int*)d_in[1];
    const int*   batch = (const int*)d_in[2];
    const float* W1    = (const float*)d_in[3];
    const float* b1    = (const float*)d_in[4];
    const float* Ws    = (const float*)d_in[5];
    const float* bs    = (const float*)d_in[6];
    const float* Wlin  = (const float*)d_in[7];
    const float* blin  = (const float*)d_in[8];
    float* out = (float*)d_out;

    const int N = in_sizes[0] / 128;
    const int E = in_sizes[1] / 2;
    const int T = in_sizes[8];           // 10
    const int G = out_size / T;          // 512

    const int packCap = E + 3 * N + 4;   // padded records + dummy chunk
    const int dummy   = E + 3 * N;       // 4 zero records live here

    // workspace layout (float offsets):
    float*  ws = (float*)d_ws;
    int*    cnt      = (int*)ws;                     // [N] histogram -> cursor (dead after fill)
    float*  Wc       = ws + 24000;                   // reuse cnt tail (dead), [128*T]
    float*  bc       = ws + 24000 + 128 * 10;        // [T]
    int*    rowptr   = (int*)(ws + 50000);           // [N+1]
    int*    bsums    = (int*)(ws + 100016);          // [256]
    int*    start    = (int*)(ws + 100272);          // [G+1]
    float2* csr_pack = (float2*)(ws + 100800);       // [packCap] -> ends 1680808
    float*  dinv     = ws + 1680816;                 // [N]
    __half* x16      = (__half*)(ws + 1730816);      // [N*128 halves] = 3.2M floats
    __half* bufA16   = (__half*)(ws + 4930816);      // [N*128 halves]
    __half* bufB16   = (__half*)(ws + 8130816);      // [N*128 halves]
    float*  pooled   = ws + 11330816;                // [G*128]

    const int* srcs = ei;
    const int* dsts = ei + E;
    const float* W4 = Ws + 2 * 16384;
    const float* b4 = bs + 2 * 128;

    hipMemsetAsync(cnt, 0, (size_t)N * sizeof(int), stream);
    hipMemsetAsync(csr_pack, 0, (size_t)packCap * sizeof(float2), stream);

    const int nb = (N + 255) / 256;
    k_count <<<(E + 255) / 256, 256, 0, stream>>>(dsts, E, cnt);
    k_scan1 <<<nb, 256, 0, stream>>>(cnt, N, rowptr, bsums, dinv);
    k_scan2 <<<1, 256, 0, stream>>>(bsums, nb);
    k_scan3 <<<nb, 256, 0, stream>>>(rowptr, bsums, cnt, N);
    k_fill  <<<(E + 255) / 256, 256, 0, stream>>>(srcs, dsts, rowptr, cnt, dinv, csr_pack, E);
    k_bounds<<<(G + 256) / 256, 256, 0, stream>>>(batch, N, G, start);
    // cnt region dead from here; Wc/bc overlap it (k_combine runs after k_fill)
    k_combine<<<(128 * T + 255) / 256, 256, 0, stream>>>(W4, Wlin, b4, blin, Wc, bc, T);
    k_cvt   <<<(N * 32 + 255) / 256, 256, 0, stream>>>(x, x16, N * 32);  // N*128/4

    const int layerBlocks = (N + 31) / 32;   // 1563, one 32-row tile each

    k_layer<<<layerBlocks, 512, 0, stream>>>(x16,    W1,         b1,       rowptr, csr_pack, dinv, dummy, bufA16, N);
    k_layer<<<layerBlocks, 512, 0, stream>>>(bufA16, Ws,         bs,       rowptr, csr_pack, dinv, dummy, bufB16, N);
    k_layer<<<layerBlocks, 512, 0, stream>>>(bufB16, Ws + 16384, bs + 128, rowptr, csr_pack, dinv, dummy, bufA16, N);
    // layer 4: gather only (fp16 -> fp16)
    const int g4blocks = (((N + 1) / 2) * 32 + 255) / 256;
    k_gather4<<<g4blocks, 256, 0, stream>>>(rowptr, csr_pack, dinv, bufA16, bufB16, dummy, N);

    k_pool_seg<<<G, 256, 0, stream>>>(bufB16, start, pooled);
    k_final   <<<G, 128, 0, stream>>>(pooled, Wc, bc, out, T);
}

// Round 13
// 279.094 us; speedup vs baseline: 1.5748x; 1.0351x over previous
//
#include <hip/hip_runtime.h>
#include <hip/hip_fp16.h>

// ---------------------------------------------------------------------------
// GCN forward, pull-based + fused. A(HW) = (AH)W:
//   per layer one kernel: gather A·H rows into LDS (branch-free padded CSR,
//   8 independent load chains; fp16 row payloads consumed via mixed-precision
//   FMA), then 128x128 fp32 matvec with W staged in two 32 KiB halves.
//   Layer 4's matvec commutes past the mean-pool:
//   out = mean(agg4)·(W4·Wlin) + (b4·Wlin + blin); the ENTIRE tail
//   (layer-4 gather + mean-pool + final matvec) is one kernel, block/graph.
// ---------------------------------------------------------------------------

__global__ void k_count(const int* __restrict__ dstv, int E, int* __restrict__ cnt) {
    int e = blockIdx.x * blockDim.x + threadIdx.x;
    if (e < E) atomicAdd(&cnt[dstv[e]], 1);
}

// scan over PADDED counts ((deg+3)&~3); also emits dinv from raw deg
__global__ void k_scan1(const int* __restrict__ cnt, int N,
                        int* __restrict__ rowptr, int* __restrict__ bsums,
                        float* __restrict__ dinv) {
    __shared__ int sh[256];
    const int t = threadIdx.x;
    const int i = blockIdx.x * 256 + t;
    const int v = (i < N) ? cnt[i] : 0;
    const int pv = (v + 3) & ~3;
    if (i < N) dinv[i] = 1.0f / sqrtf((float)(v + 1));  // +1 self loop
    sh[t] = pv;
    __syncthreads();
    for (int off = 1; off < 256; off <<= 1) {
        int add = (t >= off) ? sh[t - off] : 0;
        __syncthreads();
        sh[t] += add;
        __syncthreads();
    }
    if (i < N) rowptr[i] = sh[t] - pv;
    if (t == 255) bsums[blockIdx.x] = sh[255];
}

__global__ void k_scan2(int* __restrict__ bsums, int nb) {
    __shared__ int sh[256];
    const int t = threadIdx.x;
    const int v = (t < nb) ? bsums[t] : 0;
    sh[t] = v;
    __syncthreads();
    for (int off = 1; off < 256; off <<= 1) {
        int add = (t >= off) ? sh[t - off] : 0;
        __syncthreads();
        sh[t] += add;
        __syncthreads();
    }
    if (t < nb) bsums[t] = sh[t] - v;
}

__global__ void k_scan3(int* __restrict__ rowptr, const int* __restrict__ bsums,
                        int* __restrict__ cnt, int N) {
    const int i = blockIdx.x * blockDim.x + threadIdx.x;
    if (i < N) {
        rowptr[i] += bsums[i >> 8];
        if (i == N - 1) rowptr[N] = rowptr[i] + ((cnt[i] + 3) & ~3);
        cnt[i] = 0;                            // becomes fill cursor
    }
}

// packed edge record: .x = src index (bit pattern), .y = dinv[src]*dinv[dst]
// pad slots (memset to 0) = {src 0, weight 0.0}
__global__ void k_fill(const int* __restrict__ srcv, const int* __restrict__ dstv,
                       const int* __restrict__ rowptr, int* __restrict__ cur,
                       const float* __restrict__ dinv,
                       float2* __restrict__ csr_pack, int E) {
    int e = blockIdx.x * blockDim.x + threadIdx.x;
    if (e < E) {
        const int d = dstv[e];
        const int s = srcv[e];
        const int slot = atomicAdd(&cur[d], 1);
        float2 rec;
        rec.x = __int_as_float(s);
        rec.y = dinv[s] * dinv[d];
        csr_pack[rowptr[d] + slot] = rec;
    }
}

// store float4 as 4 halves (8B)
__device__ __forceinline__ void st_h4(__half* p, float4 v) {
    float2 raw;
    ((__half2*)&raw)[0] = __floats2half2_rn(v.x, v.y);
    ((__half2*)&raw)[1] = __floats2half2_rn(v.z, v.w);
    *(float2*)p = raw;
}

// Fused independent setup work, dispatched by blockIdx range:
//   [0, cvtB)                 : x fp32 -> fp16
//   [cvtB, cvtB+cmbB)         : Wc = W4@Wlin, bc = b4@Wlin + blin
//   [cvtB+cmbB, ...)          : start[g] = lower_bound(batch, g)
__global__ void k_setup(const float* __restrict__ x, __half* __restrict__ x16, int n4,
                        const float* __restrict__ W4, const float* __restrict__ Wlin,
                        const float* __restrict__ b4, const float* __restrict__ blin,
                        float* __restrict__ Wc, float* __restrict__ bc, int T,
                        const int* __restrict__ batch, int N, int G,
                        int* __restrict__ start, int cvtB, int cmbB)
{
    const int b = blockIdx.x;
    const int t = threadIdx.x;
    if (b < cvtB) {
        const int i = b * 256 + t;
        if (i < n4) {
            const float4 v = ((const float4*)x)[i];
            st_h4(x16 + 4 * i, v);
        }
    } else if (b < cvtB + cmbB) {
        const int idx = (b - cvtB) * 256 + t;
        if (idx < 128 * T) {
            const int k = idx / T, tt = idx % T;
            float acc = 0.f;
            #pragma unroll 8
            for (int j = 0; j < 128; ++j)
                acc = fmaf(W4[k * 128 + j], Wlin[j * T + tt], acc);
            Wc[idx] = acc;
        }
        if (idx < T) {
            float acc = blin[idx];
            #pragma unroll 8
            for (int j = 0; j < 128; ++j)
                acc = fmaf(b4[j], Wlin[j * T + idx], acc);
            bc[idx] = acc;
        }
    } else {
        const int g = (b - cvtB - cmbB) * 256 + t;
        if (g > G) return;
        int lo = 0, hi = N;
        while (lo < hi) {
            const int mid = (lo + hi) >> 1;
            if (batch[mid] < g) lo = mid + 1; else hi = mid;
        }
        start[g] = lo;
    }
}

// mixed-precision FMA: acc(f32) += s(f32) * h(fp16x4) — targets v_fma_mix_f32
__device__ __forceinline__ void fma4mix(float4& acc, float s, uint2 raw) {
    const __half* h = (const __half*)&raw;
    acc.x = fmaf(s, __half2float(h[0]), acc.x);
    acc.y = fmaf(s, __half2float(h[1]), acc.y);
    acc.z = fmaf(s, __half2float(h[2]), acc.z);
    acc.w = fmaf(s, __half2float(h[3]), acc.w);
}

// Gather aggregated rows n0 AND n1 from fp16 H, interleaved 4-wide each:
// 8 independent {record -> row} load chains. Branch-free body: rows padded
// to x4 records, exhausted rows redirect their CHUNK ADDRESS to the dummy
// zero-chunk. Row payloads consumed via mixed-precision FMA (no cvt insts).
__device__ __forceinline__ void gather_pair2(
    int n0, int n1, int v0, int v1,
    const __half* __restrict__ Hin,
    const int* __restrict__ rowptr, const float2* __restrict__ pk,
    const float* __restrict__ dinv, int lane, int dummy,
    float4& r0, float4& r1)
{
    const int nc0 = v0 ? n0 : 0;
    const int nc1 = v1 ? n1 : 0;
    const float dn0 = v0 ? dinv[nc0] : 0.f;
    const float dn1 = v1 ? dinv[nc1] : 0.f;
    int c0 = rowptr[nc0];
    int c1 = rowptr[nc1];
    const int e0 = v0 ? rowptr[nc0 + 1] : c0;
    const int e1 = v1 ? rowptr[nc1 + 1] : c1;

    const uint2 s0v = *(const uint2*)(Hin + (size_t)nc0 * 128 + 4 * lane);
    const uint2 s1v = *(const uint2*)(Hin + (size_t)nc1 * 128 + 4 * lane);
    float4 p0 = make_float4(0.f, 0.f, 0.f, 0.f);
    float4 q0 = make_float4(0.f, 0.f, 0.f, 0.f);
    float4 p1 = make_float4(0.f, 0.f, 0.f, 0.f);
    float4 q1 = make_float4(0.f, 0.f, 0.f, 0.f);
    fma4mix(p0, dn0 * dn0, s0v);
    fma4mix(q0, dn1 * dn1, s1v);

    while (c0 < e0 || c1 < e1) {
        const int a0 = (c0 < e0) ? c0 : dummy;   // chunk-level select only
        const int a1 = (c1 < e1) ? c1 : dummy;
        const float2 ra0 = pk[a0];
        const float2 ra1 = pk[a0 + 1];
        const float2 ra2 = pk[a0 + 2];
        const float2 ra3 = pk[a0 + 3];
        const float2 rb0 = pk[a1];
        const float2 rb1 = pk[a1 + 1];
        const float2 rb2 = pk[a1 + 2];
        const float2 rb3 = pk[a1 + 3];
        const uint2 va0 = *(const uint2*)(Hin + (size_t)__float_as_int(ra0.x) * 128 + 4 * lane);
        const uint2 va1 = *(const uint2*)(Hin + (size_t)__float_as_int(ra1.x) * 128 + 4 * lane);
        const uint2 va2 = *(const uint2*)(Hin + (size_t)__float_as_int(ra2.x) * 128 + 4 * lane);
        const uint2 va3 = *(const uint2*)(Hin + (size_t)__float_as_int(ra3.x) * 128 + 4 * lane);
        const uint2 vb0 = *(const uint2*)(Hin + (size_t)__float_as_int(rb0.x) * 128 + 4 * lane);
        const uint2 vb1 = *(const uint2*)(Hin + (size_t)__float_as_int(rb1.x) * 128 + 4 * lane);
        const uint2 vb2 = *(const uint2*)(Hin + (size_t)__float_as_int(rb2.x) * 128 + 4 * lane);
        const uint2 vb3 = *(const uint2*)(Hin + (size_t)__float_as_int(rb3.x) * 128 + 4 * lane);
        fma4mix(p0, ra0.y, va0); fma4mix(p1, ra1.y, va1);
        fma4mix(p0, ra2.y, va2); fma4mix(p1, ra3.y, va3);
        fma4mix(q0, rb0.y, vb0); fma4mix(q1, rb1.y, vb1);
        fma4mix(q0, rb2.y, vb2); fma4mix(q1, rb3.y, vb3);
        c0 += 4; c1 += 4;
    }
    p0.x += p1.x; p0.y += p1.y; p0.z += p1.z; p0.w += p1.w;
    q0.x += q1.x; q0.y += q1.y; q0.z += q1.z; q0.w += q1.w;
    r0 = p0;
    r1 = q0;
}

// Fused layer: Hout[n] = fp16( relu( (A·Hin)[n] @ W + bias ) ).
// One 32-row tile/block. W staged in two 64x128 halves; accumulators live
// across both passes. 48 KiB LDS, launch_bounds(512,6).
__global__ __launch_bounds__(512, 6) void k_layer(
    const __half* __restrict__ Hin, const float* __restrict__ W,
    const float* __restrict__ bias,
    const int* __restrict__ rowptr, const float2* __restrict__ csr_pack,
    const float* __restrict__ dinv, int dummy,
    __half* __restrict__ Hout, int N)
{
    __shared__ float Wl[64 * 128];    // 32 KiB: half of W [k][c]
    __shared__ float hl[32 * 128];    // 16 KiB: 32 aggregated rows (fp32)
    const int tid = threadIdx.x;
    for (int i = tid; i < 2048; i += 512)
        ((float4*)Wl)[i] = ((const float4*)W)[i];          // k rows 0..63

    const int lane = tid & 31;
    const int grp  = tid >> 5;        // 0..15
    const int rowBase = blockIdx.x << 5;

    const int n0 = rowBase + grp;
    const int n1 = rowBase + grp + 16;
    const int v0 = n0 < N, v1 = n1 < N;
    float4 g0, g1;
    gather_pair2(n0, n1, v0, v1, Hin, rowptr, csr_pack, dinv, lane, dummy, g0, g1);
    if (v0) *(float4*)(hl + grp * 128 + 4 * lane) = g0;
    if (v1) *(float4*)(hl + (grp + 16) * 128 + 4 * lane) = g1;
    __syncthreads();   // hl + Wl(half 0) ready

    float4 a0 = make_float4(0.f, 0.f, 0.f, 0.f);
    float4 a1 = make_float4(0.f, 0.f, 0.f, 0.f);
    // pass 0: k = 0..63
    #pragma unroll 4
    for (int kq = 0; kq < 16; ++kq) {
        const float4 h0 = *(const float4*)(hl + grp * 128 + 4 * kq);
        const float4 h1 = *(const float4*)(hl + (grp + 16) * 128 + 4 * kq);
        const float4* wp = ((const float4*)Wl) + (4 * kq) * 32 + lane;
        const float4 w0 = wp[0];
        const float4 w1 = wp[32];
        const float4 w2 = wp[64];
        const float4 w3 = wp[96];
        a0.x = fmaf(h0.x, w0.x, a0.x); a0.y = fmaf(h0.x, w0.y, a0.y);
        a0.z = fmaf(h0.x, w0.z, a0.z); a0.w = fmaf(h0.x, w0.w, a0.w);
        a0.x = fmaf(h0.y, w1.x, a0.x); a0.y = fmaf(h0.y, w1.y, a0.y);
        a0.z = fmaf(h0.y, w1.z, a0.z); a0.w = fmaf(h0.y, w1.w, a0.w);
        a0.x = fmaf(h0.z, w2.x, a0.x); a0.y = fmaf(h0.z, w2.y, a0.y);
        a0.z = fmaf(h0.z, w2.z, a0.z); a0.w = fmaf(h0.z, w2.w, a0.w);
        a0.x = fmaf(h0.w, w3.x, a0.x); a0.y = fmaf(h0.w, w3.y, a0.y);
        a0.z = fmaf(h0.w, w3.z, a0.z); a0.w = fmaf(h0.w, w3.w, a0.w);
        a1.x = fmaf(h1.x, w0.x, a1.x); a1.y = fmaf(h1.x, w0.y, a1.y);
        a1.z = fmaf(h1.x, w0.z, a1.z); a1.w = fmaf(h1.x, w0.w, a1.w);
        a1.x = fmaf(h1.y, w1.x, a1.x); a1.y = fmaf(h1.y, w1.y, a1.y);
        a1.z = fmaf(h1.y, w1.z, a1.z); a1.w = fmaf(h1.y, w1.w, a1.w);
        a1.x = fmaf(h1.z, w2.x, a1.x); a1.y = fmaf(h1.z, w2.y, a1.y);
        a1.z = fmaf(h1.z, w2.z, a1.z); a1.w = fmaf(h1.z, w2.w, a1.w);
        a1.x = fmaf(h1.w, w3.x, a1.x); a1.y = fmaf(h1.w, w3.y, a1.y);
        a1.z = fmaf(h1.w, w3.z, a1.z); a1.w = fmaf(h1.w, w3.w, a1.w);
    }
    __syncthreads();   // pass-0 Wl reads done
    for (int i = tid; i < 2048; i += 512)
        ((float4*)Wl)[i] = ((const float4*)(W + 64 * 128))[i];  // k rows 64..127
    __syncthreads();   // Wl(half 1) ready
    // pass 1: k = 64..127
    #pragma unroll 4
    for (int kq = 0; kq < 16; ++kq) {
        const float4 h0 = *(const float4*)(hl + grp * 128 + 64 + 4 * kq);
        const float4 h1 = *(const float4*)(hl + (grp + 16) * 128 + 64 + 4 * kq);
        const float4* wp = ((const float4*)Wl) + (4 * kq) * 32 + lane;
        const float4 w0 = wp[0];
        const float4 w1 = wp[32];
        const float4 w2 = wp[64];
        const float4 w3 = wp[96];
        a0.x = fmaf(h0.x, w0.x, a0.x); a0.y = fmaf(h0.x, w0.y, a0.y);
        a0.z = fmaf(h0.x, w0.z, a0.z); a0.w = fmaf(h0.x, w0.w, a0.w);
        a0.x = fmaf(h0.y, w1.x, a0.x); a0.y = fmaf(h0.y, w1.y, a0.y);
        a0.z = fmaf(h0.y, w1.z, a0.z); a0.w = fmaf(h0.y, w1.w, a0.w);
        a0.x = fmaf(h0.z, w2.x, a0.x); a0.y = fmaf(h0.z, w2.y, a0.y);
        a0.z = fmaf(h0.z, w2.z, a0.z); a0.w = fmaf(h0.z, w2.w, a0.w);
        a0.x = fmaf(h0.w, w3.x, a0.x); a0.y = fmaf(h0.w, w3.y, a0.y);
        a0.z = fmaf(h0.w, w3.z, a0.z); a0.w = fmaf(h0.w, w3.w, a0.w);
        a1.x = fmaf(h1.x, w0.x, a1.x); a1.y = fmaf(h1.x, w0.y, a1.y);
        a1.z = fmaf(h1.x, w0.z, a1.z); a1.w = fmaf(h1.x, w0.w, a1.w);
        a1.x = fmaf(h1.y, w1.x, a1.x); a1.y = fmaf(h1.y, w1.y, a1.y);
        a1.z = fmaf(h1.y, w1.z, a1.z); a1.w = fmaf(h1.y, w1.w, a1.w);
        a1.x = fmaf(h1.z, w2.x, a1.x); a1.y = fmaf(h1.z, w2.y, a1.y);
        a1.z = fmaf(h1.z, w2.z, a1.z); a1.w = fmaf(h1.z, w2.w, a1.w);
        a1.x = fmaf(h1.w, w3.x, a1.x); a1.y = fmaf(h1.w, w3.y, a1.y);
        a1.z = fmaf(h1.w, w3.z, a1.z); a1.w = fmaf(h1.w, w3.w, a1.w);
    }

    const float4 bv = ((const float4*)bias)[lane];
    a0.x += bv.x; a0.y += bv.y; a0.z += bv.z; a0.w += bv.w;
    a1.x += bv.x; a1.y += bv.y; a1.z += bv.z; a1.w += bv.w;
    a0.x = fmaxf(a0.x, 0.f); a0.y = fmaxf(a0.y, 0.f);
    a0.z = fmaxf(a0.z, 0.f); a0.w = fmaxf(a0.w, 0.f);
    a1.x = fmaxf(a1.x, 0.f); a1.y = fmaxf(a1.y, 0.f);
    a1.z = fmaxf(a1.z, 0.f); a1.w = fmaxf(a1.w, 0.f);
    if (v0) st_h4(Hout + (size_t)n0 * 128 + 4 * lane, a0);
    if (v1) st_h4(Hout + (size_t)n1 * 128 + 4 * lane, a1);
}

// Fused tail: block per graph. Gathers A·h3 rows of the graph, accumulating
// directly into registers (no materialization), reduces across groups,
// divides by count, applies the combined 128xT matvec.
__global__ __launch_bounds__(512) void k_tail(
    const int* __restrict__ rowptr, const float2* __restrict__ csr_pack,
    const float* __restrict__ dinv, const __half* __restrict__ Hin,
    const int* __restrict__ startv,
    const float* __restrict__ Wc, const float* __restrict__ bc,
    float* __restrict__ out, int dummy, int T)
{
    __shared__ float red[16 * 128];   // 8 KiB
    const int g = blockIdx.x;
    const int tid = threadIdx.x;
    const int lane = tid & 31;
    const int grp  = tid >> 5;        // 0..15
    const int s0 = startv[g], s1 = startv[g + 1];

    float4 acc = make_float4(0.f, 0.f, 0.f, 0.f);
    for (int r = s0 + grp; r < s1; r += 32) {   // pair (r, r+16) per iter
        const int n1 = r + 16;
        float4 r0, r1;
        gather_pair2(r, n1, 1, n1 < s1, Hin, rowptr, csr_pack, dinv, lane, dummy, r0, r1);
        acc.x += r0.x + r1.x; acc.y += r0.y + r1.y;
        acc.z += r0.z + r1.z; acc.w += r0.w + r1.w;
    }
    *(float4*)(red + grp * 128 + 4 * lane) = acc;
    __syncthreads();

    // reduce 16 partials per channel; 128 threads, one channel each
    if (tid < 128) {
        float s = 0.f;
        #pragma unroll
        for (int k = 0; k < 16; ++k)
            s += red[k * 128 + tid];
        const float inv = 1.0f / fmaxf((float)(s1 - s0), 1.0f);
        red[tid] = s * inv;           // pooled value, reuse red[0][*]
    }
    __syncthreads();

    if (tid < T) {
        float o = bc[tid];
        #pragma unroll 8
        for (int k = 0; k < 128; ++k)
            o = fmaf(red[k], Wc[k * T + tid], o);
        out[g * T + tid] = o;
    }
}

extern "C" void kernel_launch(void* const* d_in, const int* in_sizes, int n_in,
                              void* d_out, int out_size, void* d_ws, size_t ws_size,
                              hipStream_t stream)
{
    const float* x     = (const float*)d_in[0];
    const int*   ei    = (const int*)d_in[1];
    const int*   batch = (const int*)d_in[2];
    const float* W1    = (const float*)d_in[3];
    const float* b1    = (const float*)d_in[4];
    const float* Ws    = (const float*)d_in[5];
    const float* bs    = (const float*)d_in[6];
    const float* Wlin  = (const float*)d_in[7];
    const float* blin  = (const float*)d_in[8];
    float* out = (float*)d_out;

    const int N = in_sizes[0] / 128;
    const int E = in_sizes[1] / 2;
    const int T = in_sizes[8];           // 10
    const int G = out_size / T;          // 512

    const int packCap = E + 3 * N + 4;   // padded records + dummy chunk
    const int dummy   = E + 3 * N;       // 4 zero records live here

    // workspace layout (float offsets), no aliasing:
    float*  ws = (float*)d_ws;
    int*    cnt      = (int*)ws;                     // [N] histogram -> cursor
    int*    rowptr   = (int*)(ws + 50000);           // [N+1]
    int*    bsums    = (int*)(ws + 100016);          // [256]
    int*    start    = (int*)(ws + 100272);          // [G+1]
    float2* csr_pack = (float2*)(ws + 100800);       // [packCap] -> ends ~1780808
    float*  dinv     = ws + 1780816;                 // [N]
    __half* x16      = (__half*)(ws + 1830816);      // [N*128 halves] = 3.2M floats
    __half* bufA16   = (__half*)(ws + 5030816);      // [N*128 halves]
    __half* bufB16   = (__half*)(ws + 8230816);      // [N*128 halves]
    float*  Wc       = ws + 11430816;                // [128*T]
    float*  bc       = ws + 11430816 + 128 * 10;     // [T]

    const int* srcs = ei;
    const int* dsts = ei + E;
    const float* W4 = Ws + 2 * 16384;
    const float* b4 = bs + 2 * 128;

    hipMemsetAsync(cnt, 0, (size_t)N * sizeof(int), stream);
    hipMemsetAsync(csr_pack, 0, (size_t)packCap * sizeof(float2), stream);

    const int nb = (N + 255) / 256;
    k_count <<<(E + 255) / 256, 256, 0, stream>>>(dsts, E, cnt);
    k_scan1 <<<nb, 256, 0, stream>>>(cnt, N, rowptr, bsums, dinv);
    k_scan2 <<<1, 256, 0, stream>>>(bsums, nb);
    k_scan3 <<<nb, 256, 0, stream>>>(rowptr, bsums, cnt, N);
    k_fill  <<<(E + 255) / 256, 256, 0, stream>>>(srcs, dsts, rowptr, cnt, dinv, csr_pack, E);

    const int cvtB = (N * 32 + 255) / 256;           // x -> x16, float4 granules
    const int cmbB = (128 * T + 255) / 256;
    const int bndB = (G + 256) / 256;
    k_setup<<<cvtB + cmbB + bndB, 256, 0, stream>>>(
        x, x16, N * 32, W4, Wlin, b4, blin, Wc, bc, T,
        batch, N, G, start, cvtB, cmbB);

    const int layerBlocks = (N + 31) / 32;   // 1563, one 32-row tile each

    k_layer<<<layerBlocks, 512, 0, stream>>>(x16,    W1,         b1,       rowptr, csr_pack, dinv, dummy, bufA16, N);
    k_layer<<<layerBlocks, 512, 0, stream>>>(bufA16, Ws,         bs,       rowptr, csr_pack, dinv, dummy, bufB16, N);
    k_layer<<<layerBlocks, 512, 0, stream>>>(bufB16, Ws + 16384, bs + 128, rowptr, csr_pack, dinv, dummy, bufA16, N);

    // fused tail: layer-4 gather + mean-pool + combined final matvec
    k_tail<<<G, 512, 0, stream>>>(rowptr, csr_pack, dinv, bufA16, start, Wc, bc, out, dummy, T);
}